// Round 2
// baseline (1170.476 us; speedup 1.0000x reference)
//
#include <hip/hip_runtime.h>

// Fused MHA (seq_len=1 variant): per batch row b:
//   mean = (o1+o2+o3)/3 reshaped (32,128); score = mean @ W @ main^T (32x32)
//   attn = softmax(score, axis=-1); out = attn @ main  -> (1,4096)
//
// Strategy: everything on bf16 MFMA (32x32x16) with hi/lo split precision
// (keep Ah*Bh + Al*Bh + Ah*Bl; dropped term ~2^-18 rel). One wave per b,
// 8 waves per block. W^T staged once per block in LDS (bf16 hi/lo, XOR
// swizzle -> ds_read_b64 at the 4-cycle wave64 bank floor). mean/main
// fragments loaded straight from global with line-exact per-lane addressing.
// M1 accumulator register-chains into M2's B fragments; M2's accumulator
// chains into softmax (lane-local h) and M3's A fragments. No intermediate
// tensors touch memory. o1/o2/o3 loads + out stores are nontemporal
// (streamed exactly once) to keep L2/L3 for W and the re-read main rows.

typedef __attribute__((ext_vector_type(8)))  __bf16         bf16x8;
typedef __attribute__((ext_vector_type(8)))  unsigned short us8;
typedef __attribute__((ext_vector_type(4)))  unsigned short us4;
typedef __attribute__((ext_vector_type(4)))  float          f32x4;
typedef __attribute__((ext_vector_type(16))) float          f32x16;

static __device__ __forceinline__ unsigned short f2bf(float x) {
  unsigned u = __builtin_bit_cast(unsigned, x);
  return (unsigned short)((u + 0x7fffu + ((u >> 16) & 1u)) >> 16);  // RNE
}
static __device__ __forceinline__ float bf2f(unsigned short h) {
  unsigned u = ((unsigned)h) << 16;
  return __builtin_bit_cast(float, u);
}

#define MFMA(a, b, c) __builtin_amdgcn_mfma_f32_32x32x16_bf16((a), (b), (c), 0, 0, 0)

__global__ __launch_bounds__(512, 2)
void mha_fused(const float* __restrict__ o1, const float* __restrict__ o2,
               const float* __restrict__ o3, const float* __restrict__ mainp,
               const float* __restrict__ W, float* __restrict__ out)
{
  // W^T as bf16 hi/lo, row = e (0..127), 128 shorts per row, XOR-swizzled.
  __shared__ unsigned short WTh[128 * 128];
  __shared__ unsigned short WTl[128 * 128];

  const int tid = threadIdx.x;

  // ---------------- Stage W^T (once per block) ----------------
  #pragma unroll
  for (int it = 0; it < 8; ++it) {
    int f  = (tid + it * 512) * 4;   // flat index into W[d][e], 4 at a time
    int d  = f >> 7;
    int e0 = f & 127;
    f32x4 w4 = *reinterpret_cast<const f32x4*>(W + f);
    #pragma unroll
    for (int j = 0; j < 4; ++j) {
      int e = e0 + j;
      float x = w4[j];
      unsigned short hi = f2bf(x);
      unsigned short lo = f2bf(x - bf2f(hi));
      // byte-in-row = (2*d) ^ ((e&15)<<3); stored as short index
      int sidx = e * 128 + (((2 * d) ^ ((e & 15) << 3)) >> 1);
      WTh[sidx] = hi;
      WTl[sidx] = lo;
    }
  }
  __syncthreads();

  const int wid  = tid >> 6;     // wave id 0..7 -> which b
  const int lane = tid & 63;
  const int l31  = lane & 31;
  const int lh   = lane >> 5;    // 0/1

  const int b = blockIdx.x * 8 + wid;
  const float* o1b = o1 + (size_t)b * 4096;
  const float* o2b = o2 + (size_t)b * 4096;
  const float* o3b = o3 + (size_t)b * 4096;
  const float* mb  = mainp + (size_t)b * 4096;
  float*       ob  = out + (size_t)b * 4096;

  // ---------------- M1: mWT[e][h] = sum_d W[d][e] * mean[h][d] ----------------
  // A = W^T (M=e:128 -> 4 tiles), B = mean^T (N=h:32), K = d:128 -> 8 chunks.
  f32x16 acc[4] = {};

  #pragma unroll
  for (int kc = 0; kc < 8; ++kc) {
    const int d0 = kc * 16 + lh * 4;
    const int ro = l31 * 128 + d0;       // row h = l31 of the o-arrays
    f32x4 x0 = __builtin_nontemporal_load(reinterpret_cast<const f32x4*>(o1b + ro));
    f32x4 y0 = __builtin_nontemporal_load(reinterpret_cast<const f32x4*>(o2b + ro));
    f32x4 z0 = __builtin_nontemporal_load(reinterpret_cast<const f32x4*>(o3b + ro));
    f32x4 x1 = __builtin_nontemporal_load(reinterpret_cast<const f32x4*>(o1b + ro + 8));
    f32x4 y1 = __builtin_nontemporal_load(reinterpret_cast<const f32x4*>(o2b + ro + 8));
    f32x4 z1 = __builtin_nontemporal_load(reinterpret_cast<const f32x4*>(o3b + ro + 8));
    us8 mh, ml;
    #pragma unroll
    for (int j = 0; j < 4; ++j) {
      float m0 = (x0[j] + y0[j] + z0[j]) * (1.0f / 3.0f);
      float m1 = (x1[j] + y1[j] + z1[j]) * (1.0f / 3.0f);
      unsigned short h0 = f2bf(m0), h1 = f2bf(m1);
      mh[j]     = h0;  ml[j]     = f2bf(m0 - bf2f(h0));
      mh[j + 4] = h1;  ml[j + 4] = f2bf(m1 - bf2f(h1));
    }
    bf16x8 Bh = __builtin_bit_cast(bf16x8, mh);
    bf16x8 Bl = __builtin_bit_cast(bf16x8, ml);

    #pragma unroll
    for (int et = 0; et < 4; ++et) {
      const int e  = et * 32 + l31;
      const int sw = (e & 15) << 3;
      const int rb = e * 128;
      const int iA = rb + (((2 * d0) ^ sw) >> 1);
      const int iB = rb + (((2 * (d0 + 8)) ^ sw) >> 1);
      us4 ah0 = *reinterpret_cast<const us4*>(&WTh[iA]);
      us4 ah1 = *reinterpret_cast<const us4*>(&WTh[iB]);
      us4 al0 = *reinterpret_cast<const us4*>(&WTl[iA]);
      us4 al1 = *reinterpret_cast<const us4*>(&WTl[iB]);
      us8 ahv, alv;
      #pragma unroll
      for (int j = 0; j < 4; ++j) {
        ahv[j] = ah0[j]; ahv[j + 4] = ah1[j];
        alv[j] = al0[j]; alv[j + 4] = al1[j];
      }
      bf16x8 Ah = __builtin_bit_cast(bf16x8, ahv);
      bf16x8 Al = __builtin_bit_cast(bf16x8, alv);
      acc[et] = MFMA(Ah, Bh, acc[et]);
      acc[et] = MFMA(Al, Bh, acc[et]);
      acc[et] = MFMA(Ah, Bl, acc[et]);
    }
  }

  // ---------------- M2: score^T[g][h] = sum_e main[g][e] * mWT[e][h] ----------------
  // A = main (M=g:32), B = mWT from acc regs (N=h:32), K=e:128.
  // B-frag(kcc) = acc[kcc>>1] regs [8*(kcc&1) .. +7] (register chain, derived
  // from D layout col=l&31,row=(r&3)+8*(r>>2)+4*(l>>5)).
  f32x16 sacc = {};
  #pragma unroll
  for (int kcc = 0; kcc < 8; ++kcc) {
    const int e0 = kcc * 16 + lh * 4;
    const int ro = l31 * 128 + e0;       // row g = l31 of main
    f32x4 g0 = *reinterpret_cast<const f32x4*>(mb + ro);
    f32x4 g1 = *reinterpret_cast<const f32x4*>(mb + ro + 8);
    us8 ah, al, bh, bl;
    #pragma unroll
    for (int j = 0; j < 4; ++j) {
      float v0 = g0[j], v1 = g1[j];
      unsigned short h0 = f2bf(v0), h1 = f2bf(v1);
      ah[j]     = h0;  al[j]     = f2bf(v0 - bf2f(h0));
      ah[j + 4] = h1;  al[j + 4] = f2bf(v1 - bf2f(h1));
    }
    const int et = kcc >> 1;
    const int rbase = (kcc & 1) * 8;
    #pragma unroll
    for (int i = 0; i < 8; ++i) {
      float v = acc[et][rbase + i];
      unsigned short h = f2bf(v);
      bh[i] = h;  bl[i] = f2bf(v - bf2f(h));
    }
    bf16x8 Ah = __builtin_bit_cast(bf16x8, ah);
    bf16x8 Al = __builtin_bit_cast(bf16x8, al);
    bf16x8 Bh = __builtin_bit_cast(bf16x8, bh);
    bf16x8 Bl = __builtin_bit_cast(bf16x8, bl);
    sacc = MFMA(Ah, Bh, sacc);
    sacc = MFMA(Al, Bh, sacc);
    sacc = MFMA(Ah, Bl, sacc);
  }

  // ---------------- softmax over g (lane-local 16 + partner lane^32) ----------------
  float mx = sacc[0];
  #pragma unroll
  for (int r = 1; r < 16; ++r) mx = fmaxf(mx, sacc[r]);
  mx = fmaxf(mx, __shfl_xor(mx, 32));
  float p[16];
  float s = 0.0f;
  #pragma unroll
  for (int r = 0; r < 16; ++r) { p[r] = __expf(sacc[r] - mx); s += p[r]; }
  s += __shfl_xor(s, 32);
  const float inv = 1.0f / s;

  // attn -> A-fragments for M3: frag(kcg) elem i = p[8*kcg + i]
  us8 pah[2], pal[2];
  #pragma unroll
  for (int kcg = 0; kcg < 2; ++kcg) {
    #pragma unroll
    for (int i = 0; i < 8; ++i) {
      float v = p[kcg * 8 + i] * inv;
      unsigned short h = f2bf(v);
      pah[kcg][i] = h;
      pal[kcg][i] = f2bf(v - bf2f(h));
    }
  }

  // ---------------- M3: context[h][d] = sum_g attn[h][g] * main[g][d] ----------------
  // A = attn (regs), B = main (K=g:32, N=d:128 -> 4 tiles), per-lane gathers
  // (L1/L2-hot; 128B-contiguous per 32-lane half).
  #pragma unroll
  for (int nt = 0; nt < 4; ++nt) {
    f32x16 cacc = {};
    const int dcol = nt * 32 + l31;
    #pragma unroll
    for (int kcg = 0; kcg < 2; ++kcg) {
      const int gb = kcg * 16 + lh * 4;
      us8 bh, bl;
      #pragma unroll
      for (int i = 0; i < 8; ++i) {
        const int g = gb + (i & 3) + 8 * (i >> 2);
        float v = mb[g * 128 + dcol];
        unsigned short h = f2bf(v);
        bh[i] = h;  bl[i] = f2bf(v - bf2f(h));
      }
      bf16x8 Bh = __builtin_bit_cast(bf16x8, bh);
      bf16x8 Bl = __builtin_bit_cast(bf16x8, bl);
      bf16x8 Ah = __builtin_bit_cast(bf16x8, pah[kcg]);
      bf16x8 Al = __builtin_bit_cast(bf16x8, pal[kcg]);
      cacc = MFMA(Ah, Bh, cacc);
      cacc = MFMA(Al, Bh, cacc);
      cacc = MFMA(Ah, Bl, cacc);
    }
    #pragma unroll
    for (int r = 0; r < 16; ++r) {
      const int h = (r & 3) + 8 * (r >> 2) + 4 * lh;
      __builtin_nontemporal_store(cacc[r], ob + h * 128 + dcol);
    }
  }
}

extern "C" void kernel_launch(void* const* d_in, const int* in_sizes, int n_in,
                              void* d_out, int out_size, void* d_ws, size_t ws_size,
                              hipStream_t stream) {
  const float* o1 = (const float*)d_in[0];
  const float* o2 = (const float*)d_in[1];
  const float* o3 = (const float*)d_in[2];
  const float* mn = (const float*)d_in[3];
  const float* W  = (const float*)d_in[4];
  float* out = (float*)d_out;

  const int B = in_sizes[3] / 4096;   // 16384
  dim3 grid(B / 8);                   // one wave per batch row, 8 per block
  dim3 block(512);
  hipLaunchKernelGGL(mha_fused, grid, block, 0, stream, o1, o2, o3, mn, W, out);
}